// Round 7
// baseline (500.382 us; speedup 1.0000x reference)
//
#include <hip/hip_runtime.h>
#include <math.h>

#define L2C   65536
#define NC    (2 * L2C)
#define FINC  8
#define FOUTC 8
#define KC    13
#define BLOCK 256
#define EPB   64                      // edges per block (213 KB mask span)
#define CHUNKS (EPB * 832 / 64)       // 832 u64 bitmap chunks per block
#define CPW    (CHUNKS / 4)           // 208 chunks (streaming iters) per wave

constexpr double E_D = 2.71828182845904523536;
constexpr float SCALE_F = (float)((2.0 + 2.0 * E_D) / (E_D - 1.0));

// d_ws: xt = x transposed to (N, FIN), 4 MiB at offset 0.
__global__ __launch_bounds__(256)
void transpose_x_kernel(const float* __restrict__ x, float* __restrict__ xt) {
    int n = blockIdx.x * 256 + threadIdx.x;
    float v[FINC];
#pragma unroll
    for (int i = 0; i < FINC; ++i) v[i] = x[(size_t)i * NC + n];
    float4* dst = reinterpret_cast<float4*>(xt + ((size_t)n << 3));
    dst[0] = make_float4(v[0], v[1], v[2], v[3]);
    dst[1] = make_float4(v[4], v[5], v[6], v[7]);
}

// Phase 1: pure streaming — per wave 208 contiguous, independent dword loads
// (53 KB span), ballot-packed into an aligned u64 bitmap in LDS (no atomics:
// each chunk is written exactly once). Phase 2: per wave 16 edges, bits +
// ker from LDS, xt gathers, fma, shfl-reduce, coalesced row stores.
__global__ __launch_bounds__(BLOCK, 8)
void edge_conv_kernel(const float* __restrict__ xt,
                      const float* __restrict__ Wh, const float* __restrict__ Wv,
                      const float* __restrict__ bh, const float* __restrict__ bv,
                      const unsigned char* __restrict__ mh,
                      const unsigned char* __restrict__ mv,
                      const int* __restrict__ kh, const int* __restrict__ kv,
                      float* __restrict__ out)
{
    __shared__ unsigned long long bitbuf[CHUNKS];      // 6656 B: flat mask bits
    __shared__ float Wsh[FOUTC * FINC * KC];           // 3328 B
    __shared__ int   kersh[EPB * KC];                  // 3328 B
    __shared__ float resbuf[FOUTC * 68];               // 2176 B (pad 68 vs bank alias)

    const int tid  = threadIdx.x;
    const int lane = tid & 63;
    const int w    = tid >> 6;
    const int o    = lane >> 3;
    const int i    = lane & 7;

    const int blk = blockIdx.x;
    const int blocks_per_branch = L2C / EPB;           // 1024
    const bool hor = (blk < blocks_per_branch);

    const float*         W    = hor ? Wh  : Wv;
    const float*         bias = hor ? bh  : bv;
    const unsigned char* mask = hor ? mh  : mv;
    const int*           ker  = hor ? kh  : kv;
    const int bblk = hor ? blk : blk - blocks_per_branch;
    const int be0  = bblk * EPB;                       // first edge (branch-local)
    const int col0 = hor ? be0 : be0 + L2C;            // first output column

    // Stage W and ker rows into LDS.
    for (int j = tid; j < FOUTC * FINC * KC; j += BLOCK) Wsh[j] = W[j];
    for (int j = tid; j < EPB * KC; j += BLOCK) kersh[j] = ker[(size_t)be0 * KC + j];

    // In-wave mask-encoding probe (fixed hot 256 B window of mh): for int32
    // 0/1 and float32 0.0/1.0f every byte at offset%4==1 is zero; for 1-byte
    // bools those are random 0/1 (P[all-zero] = 2^-64, uniform across waves).
    const unsigned char probe = mh[(size_t)(lane * 4 + 1)];
    const bool words = (__ballot(probe != 0) == 0ull);

    // ---- phase 1: stream this wave's 53 KB mask span -> bitmap ----
    if (words) {
        const unsigned int* mw =
            reinterpret_cast<const unsigned int*>(mask) + (size_t)be0 * 832;
#pragma unroll 8
        for (int t = 0; t < CPW; ++t) {
            const int chunk = w * CPW + t;
            unsigned int v = mw[(size_t)chunk * 64 + lane];   // coalesced 256 B
            unsigned long long bal = __ballot(v != 0u);       // 64 words -> 64 bits
            if (lane == 0) bitbuf[chunk] = bal;
        }
    } else {
        const unsigned char* mb = mask + (size_t)be0 * 832;
#pragma unroll 8
        for (int t = 0; t < CPW; ++t) {
            const int chunk = w * CPW + t;
            unsigned char v = mb[(size_t)chunk * 64 + lane];
            unsigned long long bal = __ballot(v != 0);
            if (lane == 0) bitbuf[chunk] = bal;
        }
    }
    __syncthreads();

    // ---- phase 2: 16 edges per wave ----
    float wreg[KC];
#pragma unroll
    for (int k = 0; k < KC; ++k) wreg[k] = Wsh[lane * KC + k];   // 2-way alias: free
    const float bo = bias[o];

    const unsigned int* bb32 = reinterpret_cast<const unsigned int*>(bitbuf);
#pragma unroll 4
    for (int e8 = 0; e8 < 16; ++e8) {
        const int e    = w * 16 + e8;
        const int flat = e * 832 + lane * KC;          // flat bit index of k=0
        const int dw   = flat >> 5;
        const unsigned int lo32 = bb32[dw];
        // dw+1 can touch one dword past bitbuf (lands in Wsh, defined memory);
        // in exactly those cases shift<=19 so hi bits are never used.
        const unsigned int hi32 = bb32[dw + 1];
        const unsigned long long both =
            (unsigned long long)lo32 | ((unsigned long long)hi32 << 32);
        const unsigned int mbits = (unsigned int)(both >> (flat & 31)) & 0x1FFFu;

        float acc = 0.0f;
#pragma unroll
        for (int k = 0; k < KC; ++k) {
            const int c    = kersh[e * KC + k];        // LDS broadcast read
            const float xv = xt[((size_t)c << 3) + i]; // one 32 B seg / wave / k
            acc = fmaf(((mbits >> k) & 1u) ? wreg[k] : 0.0f, xv, acc);
        }
        acc += __shfl_xor(acc, 1);
        acc += __shfl_xor(acc, 2);
        acc += __shfl_xor(acc, 4);
        if (i == 0) resbuf[o * 68 + e] = acc + bo;
    }
    __syncthreads();

    // Coalesced row stores: 8 rows x 64 consecutive floats.
    for (int j = tid; j < FOUTC * EPB; j += BLOCK) {
        const int oo = j >> 6, e = j & 63;
        const float z   = resbuf[oo * 68 + e];
        const float sig = 1.0f / (1.0f + __expf(-z));
        out[(size_t)oo * NC + col0 + e] = (sig - 0.5f) * SCALE_F;
    }
}

extern "C" void kernel_launch(void* const* d_in, const int* in_sizes, int n_in,
                              void* d_out, int out_size, void* d_ws, size_t ws_size,
                              hipStream_t stream) {
    const float*         x   = (const float*)d_in[0];
    const float*         Wh  = (const float*)d_in[1];
    const float*         Wv  = (const float*)d_in[2];
    const float*         bh  = (const float*)d_in[3];
    const float*         bv  = (const float*)d_in[4];
    const unsigned char* mh  = (const unsigned char*)d_in[5];
    const unsigned char* mv  = (const unsigned char*)d_in[6];
    const int*           kh  = (const int*)d_in[7];
    const int*           kv  = (const int*)d_in[8];
    float* out = (float*)d_out;
    float* xt  = (float*)d_ws;

    transpose_x_kernel<<<NC / 256, 256, 0, stream>>>(x, xt);
    edge_conv_kernel<<<NC / EPB, BLOCK, 0, stream>>>(
        xt, Wh, Wv, bh, bv, mh, mv, kh, kv, out);
}

// Round 8
// 450.322 us; speedup vs baseline: 1.1112x; 1.1112x over previous
//
#include <hip/hip_runtime.h>
#include <math.h>

#define L2C   65536
#define NC    (2 * L2C)
#define FINC  8
#define FOUTC 8
#define KC    13
#define BLOCK 256         // 4 waves = 4 edges per block (1 edge per wave)
#define EPB   4

constexpr double E_D = 2.71828182845904523536;
constexpr float SCALE_F = (float)((2.0 + 2.0 * E_D) / (E_D - 1.0));

// d_ws: xt = x transposed to (N, FIN), 4 MiB at offset 0.

// x (FIN, N) -> xt (N, FIN): a gathered column becomes one 32 B segment.
__global__ __launch_bounds__(256)
void transpose_x_kernel(const float* __restrict__ x, float* __restrict__ xt) {
    int n = blockIdx.x * 256 + threadIdx.x;
    float v[FINC];
#pragma unroll
    for (int i = 0; i < FINC; ++i) v[i] = x[(size_t)i * NC + n];
    float4* dst = reinterpret_cast<float4*>(xt + ((size_t)n << 3));
    dst[0] = make_float4(v[0], v[1], v[2], v[3]);
    dst[1] = make_float4(v[4], v[5], v[6], v[7]);
}

// One wave per edge. lane = o*8 + i. Mask words for the edge are 832
// contiguous dwords -> 13 fully-coalesced dword loads + __ballot bit-packing.
// Best-measured structure (R3/R6: 139-146 us, ~3.1-3.2 TB/s effective mask
// read — the measured read-stream ceiling; see R4/R5/R7 experiments).
__global__ __launch_bounds__(BLOCK)
void edge_conv_kernel(const float* __restrict__ xt,
                      const float* __restrict__ Wh, const float* __restrict__ Wv,
                      const float* __restrict__ bh, const float* __restrict__ bv,
                      const unsigned char* __restrict__ mh,
                      const unsigned char* __restrict__ mv,
                      const int* __restrict__ kh, const int* __restrict__ kv,
                      float* __restrict__ out)
{
    __shared__ float Wsh[FOUTC * FINC * KC];   // flat [o][i][k], same as input

    const int tid  = threadIdx.x;
    const int lane = tid & 63;
    const int o    = lane >> 3;
    const int i    = lane & 7;

    const int blk = blockIdx.x;
    const int blocks_per_branch = L2C / EPB;   // 16384
    const bool hor = (blk < blocks_per_branch);

    const float*         W    = hor ? Wh  : Wv;
    const float*         bias = hor ? bh  : bv;
    const unsigned char* mask = hor ? mh  : mv;
    const int*           ker  = hor ? kh  : kv;
    const int bblk = hor ? blk : blk - blocks_per_branch;
    const int be   = bblk * EPB + (tid >> 6);  // edge index within branch
    const int col  = hor ? be : (be + L2C);    // edge lists are arange / arange+L2

    // Stage W into LDS (identical flat layout).
    for (int j = tid; j < FOUTC * FINC * KC; j += BLOCK) Wsh[j] = W[j];

    // In-wave mask-encoding probe (fixed hot 256 B window of mh): for int32
    // 0/1 and float32 0.0/1.0f every byte at offset%4==1 is zero; for 1-byte
    // bools they're random 0/1 (P[all 64 samples zero] = 2^-64, and every
    // wave reads the same window so the branch is grid-uniform).
    const unsigned char probe = mh[(size_t)(lane * 4 + 1)];
    const bool words = (__ballot(probe != 0) == 0ull);

    __syncthreads();

    // ---- mask bits: lane t<13 keeps ballot t (bit l = flat word t*64+l) ----
    unsigned long long myb = 0;
    if (words) {
        const unsigned int* mw = reinterpret_cast<const unsigned int*>(mask)
                                 + (size_t)be * 832 + lane;
#pragma unroll
        for (int t = 0; t < KC; ++t) {
            unsigned long long bal = __ballot(mw[t * 64] != 0u);   // coalesced
            if (lane == t) myb = bal;
        }
    } else {
        const unsigned char* mb = mask + (size_t)be * 832 + lane;
#pragma unroll
        for (int t = 0; t < KC; ++t) {
            unsigned long long bal = __ballot(mb[t * 64] != 0);
            if (lane == t) myb = bal;
        }
    }

    // Kernel column indices (wave-uniform address -> scalar loads).
    int cols[KC];
#pragma unroll
    for (int k = 0; k < KC; ++k) cols[k] = ker[(size_t)be * KC + k];

    // Extract this lane's 13 row bits (flat bits lane*13 .. lane*13+12).
    const int s     = lane * KC;
    const int u0    = s >> 6;                  // 0..12
    const int shift = s & 63;
    unsigned long long lo = __shfl(myb, u0);
    unsigned long long hi = __shfl(myb, u0 + 1);   // lane 13 holds 0, safe
    unsigned int mbits = (unsigned int)(lo >> shift);
    if (shift) mbits |= (unsigned int)(hi << (64 - shift));
    mbits &= 0x1FFFu;

    float acc = 0.0f;
#pragma unroll
    for (int k = 0; k < KC; ++k) {
        const float xv = xt[((size_t)cols[k] << 3) + i];   // one 32 B seg / wave / k
        const float wk = Wsh[lane * KC + k];               // 2-way LDS alias: free
        const float wm = ((mbits >> k) & 1u) ? wk : 0.0f;
        acc = fmaf(wm, xv, acc);
    }

    // Reduce over i (lanes o*8 .. o*8+7).
    acc += __shfl_xor(acc, 1);
    acc += __shfl_xor(acc, 2);
    acc += __shfl_xor(acc, 4);

    if (i == 0) {
        const float z   = acc + bias[o];
        const float sig = 1.0f / (1.0f + __expf(-z));
        out[(size_t)o * NC + col] = (sig - 0.5f) * SCALE_F;
    }
}

extern "C" void kernel_launch(void* const* d_in, const int* in_sizes, int n_in,
                              void* d_out, int out_size, void* d_ws, size_t ws_size,
                              hipStream_t stream) {
    const float*         x   = (const float*)d_in[0];
    const float*         Wh  = (const float*)d_in[1];
    const float*         Wv  = (const float*)d_in[2];
    const float*         bh  = (const float*)d_in[3];
    const float*         bv  = (const float*)d_in[4];
    const unsigned char* mh  = (const unsigned char*)d_in[5];
    const unsigned char* mv  = (const unsigned char*)d_in[6];
    const int*           kh  = (const int*)d_in[7];
    const int*           kv  = (const int*)d_in[8];
    float* out = (float*)d_out;
    float* xt  = (float*)d_ws;

    transpose_x_kernel<<<NC / 256, 256, 0, stream>>>(x, xt);
    edge_conv_kernel<<<NC / EPB, BLOCK, 0, stream>>>(
        xt, Wh, Wv, bh, bv, mh, mv, kh, kv, out);
}